// Round 8
// baseline (11353.619 us; speedup 1.0000x reference)
//
#include <hip/hip_runtime.h>
#include <math.h>

// Problem dims
#define B_   256
#define T_   512
#define F_   64
#define H1_  100
#define H2_  128
#define OUT_ 19
#define G1_  400   // 4*H1
#define G2_  512   // 4*H2
#define TC   16    // timesteps per chunk
#define NCHUNK (T_/TC)
#define NT   256   // threads per block (4 waves) -> predicted 256-VGPR grant

// Row splits: U rows [0,RREG) in registers (x2 cols), rest streamed from LDS
#define U1_RREG 72   // LDS part: rows 72..99  (28 x 400 = 11200 fl)
#define U2_RREG 80   // LDS part: rows 80..127 (48 x 512 = 24576 fl)

// ---- LDS layout (float indices) ----
// region1 [0,8192): A-phase xs[1024]@0 + xp1[6400]@1024 ; B-phase xp2[8192]@0
#define OFF_XS    0
#define OFF_XP1   1024
#define OFF_XP2   0
#define OFF_H1C   8192                    // TC*H1_ = 1600
#define OFF_WLDS  9792                    // max(11200, 24576) = 24576
#define OFF_ZBUF  (OFF_WLDS + 24576)      // 34368, 512
#define OFF_H1S   (OFF_ZBUF + 512)        // 34880, 128 (100 used)
#define OFF_H2S   (OFF_H1S + 128)         // 35008, 128
#define LDS_FLOATS (OFF_H2S + 128)        // 35136 fl = 140544 B (<=163840)

__device__ __forceinline__ float sigm(float x) {
    return 1.0f / (1.0f + __expf(-x));
}

// Compiler fence: caps the number of weight loads in flight (address-reg spike).
#define FENCE asm volatile("" ::: "memory");

#define DECL2(n) float4 wa##n, wb##n;
#define REP9(M)  M(0) M(1) M(2) M(3) M(4) M(5) M(6) M(7) M(8)
#define REP16(M) REP9(M) M(9) M(10) M(11) M(12) M(13) M(14) M(15)
#define REP18(M) REP16(M) M(16) M(17)
#define REP20(M) REP18(M) M(18) M(19)

// load f4 group n (rows R0+4n..R0+4n+3) of cols ca/cb from P (row stride S)
#define LD2(n,P,S,R0,ca,cb) \
  wa##n = make_float4((P)[(R0+4*n+0)*(S)+(ca)], (P)[(R0+4*n+1)*(S)+(ca)], \
                      (P)[(R0+4*n+2)*(S)+(ca)], (P)[(R0+4*n+3)*(S)+(ca)]); \
  wb##n = make_float4((P)[(R0+4*n+0)*(S)+(cb)], (P)[(R0+4*n+1)*(S)+(cb)], \
                      (P)[(R0+4*n+2)*(S)+(cb)], (P)[(R0+4*n+3)*(S)+(cb)]);

#define LS16(P,S,R0,ca,cb) \
  LD2(0,P,S,R0,ca,cb) LD2(1,P,S,R0,ca,cb) FENCE LD2(2,P,S,R0,ca,cb) LD2(3,P,S,R0,ca,cb) FENCE \
  LD2(4,P,S,R0,ca,cb) LD2(5,P,S,R0,ca,cb) FENCE LD2(6,P,S,R0,ca,cb) LD2(7,P,S,R0,ca,cb) FENCE \
  LD2(8,P,S,R0,ca,cb) LD2(9,P,S,R0,ca,cb) FENCE LD2(10,P,S,R0,ca,cb) LD2(11,P,S,R0,ca,cb) FENCE \
  LD2(12,P,S,R0,ca,cb) LD2(13,P,S,R0,ca,cb) FENCE LD2(14,P,S,R0,ca,cb) LD2(15,P,S,R0,ca,cb) FENCE
#define LS18(P,S,R0,ca,cb) LS16(P,S,R0,ca,cb) LD2(16,P,S,R0,ca,cb) LD2(17,P,S,R0,ca,cb) FENCE
#define LS20(P,S,R0,ca,cb) LS18(P,S,R0,ca,cb) LD2(18,P,S,R0,ca,cb) LD2(19,P,S,R0,ca,cb) FENCE
#define LS9(P,S,R0,ca,cb) \
  LD2(0,P,S,R0,ca,cb) LD2(1,P,S,R0,ca,cb) FENCE LD2(2,P,S,R0,ca,cb) LD2(3,P,S,R0,ca,cb) FENCE \
  LD2(4,P,S,R0,ca,cb) LD2(5,P,S,R0,ca,cb) FENCE LD2(6,P,S,R0,ca,cb) LD2(7,P,S,R0,ca,cb) FENCE \
  LD2(8,P,S,R0,ca,cb) FENCE

// dual-column FMA group: h broadcast shared by both columns
#define DOT2(n) { float4 hv_ = hb4[n]; \
  p0 += hv_.x*wa##n.x; p1 += hv_.y*wa##n.y; p2 += hv_.z*wa##n.z; p3 += hv_.w*wa##n.w; \
  q0 += hv_.x*wb##n.x; q1 += hv_.y*wb##n.y; q2 += hv_.z*wb##n.z; q3 += hv_.w*wb##n.w; }

__global__ __launch_bounds__(NT, 2)
void lstm_fused(
    const float* __restrict__ x,
    const float* __restrict__ W1, const float* __restrict__ U1, const float* __restrict__ b1,
    const float* __restrict__ W2, const float* __restrict__ U2, const float* __restrict__ b2,
    const float* __restrict__ Wd, const float* __restrict__ bd,
    float* __restrict__ out)
{
    __shared__ float lds[LDS_FLOATS];
    const int b = blockIdx.x;
    const int j = threadIdx.x;

    REP20(DECL2)            // wa0..wa19, wb0..wb19 (max 40 f4 live = 160 regs)
    float c1 = 0.0f;        // cell state, gate thread j<100 owns c1[j]
    float c2 = 0.0f;        // cell state, gate thread j<128 owns c2[j]

    // G1 phases: thread j<200 owns cols (j, j+200). G2 phases: cols (j, j+256).
    const int ca1 = j, cb1 = j + 200;
    const int ca2 = j, cb2 = j + 256;

    if (j < 128) { lds[OFF_H1S + j] = 0.0f; lds[OFF_H2S + j] = 0.0f; }
    __syncthreads();

    const float* xrow = x + (size_t)b * T_ * F_;

    for (int ch = 0; ch < NCHUNK; ++ch) {
        // ---- stage xs: TC*F_ = 1024 fl = 256 f4, 1/thread ----
        ((float4*)&lds[OFF_XS])[j] = ((const float4*)(xrow + ch * TC * F_))[j];
        // ---- stage WLDS = U1 rows 72..99 (2800 f4) ----
        {
            const float4* s4 = (const float4*)(U1 + U1_RREG * G1_);
            float4* d4 = (float4*)&lds[OFF_WLDS];
            #pragma unroll
            for (int r = 0; r < 11; ++r) {
                int idx = r * NT + j;
                if (idx < 2800) d4[idx] = s4[idx];
            }
        }
        // ---- W1 cols ca1/cb1: rows 0..63 (16 f4 x2) ----
        if (j < 200) { LS16(W1, G1_, 0, ca1, cb1) }
        __syncthreads();   // xs + WLDS(U1part) ready; prev chunk's B reads done

        // ---- A0: xp1[t][c] = b1[c] + x_t . W1col ----
        if (j < 200) {
            const float ba = b1[ca1], bb = b1[cb1];
            for (int t = 0; t < TC; ++t) {
                const float4* hb4 = (const float4*)&lds[OFF_XS + t * F_];
                float p0 = ba, p1 = 0.f, p2 = 0.f, p3 = 0.f;
                float q0 = bb, q1 = 0.f, q2 = 0.f, q3 = 0.f;
                REP16(DOT2)
                lds[OFF_XP1 + t * G1_ + ca1] = (p0 + p1) + (p2 + p3);
                lds[OFF_XP1 + t * G1_ + cb1] = (q0 + q1) + (q2 + q3);
            }
            // U1 rows 0..71 into regs (18 f4 x2)
            LS18(U1, G1_, 0, ca1, cb1)
        }
        __syncthreads();   // xp1 ready

        // ---- A1: layer-1 recurrence ----
        for (int t = 0; t < TC; ++t) {
            if (j < 200) {
                const float4* hb4 = (const float4*)&lds[OFF_H1S];
                float p0 = lds[OFF_XP1 + t * G1_ + ca1], p1 = 0.f, p2 = 0.f, p3 = 0.f;
                float q0 = lds[OFF_XP1 + t * G1_ + cb1], q1 = 0.f, q2 = 0.f, q3 = 0.f;
                REP18(DOT2)                        // rows 0..71 from regs
                #pragma unroll
                for (int m = 0; m < H1_ - U1_RREG; m += 4) {  // rows 72..99 from LDS
                    float h0 = lds[OFF_H1S + U1_RREG + m    ];
                    float h1 = lds[OFF_H1S + U1_RREG + m + 1];
                    float h2 = lds[OFF_H1S + U1_RREG + m + 2];
                    float h3 = lds[OFF_H1S + U1_RREG + m + 3];
                    p0 += h0 * lds[OFF_WLDS + (m    ) * G1_ + ca1];
                    p1 += h1 * lds[OFF_WLDS + (m + 1) * G1_ + ca1];
                    p2 += h2 * lds[OFF_WLDS + (m + 2) * G1_ + ca1];
                    p3 += h3 * lds[OFF_WLDS + (m + 3) * G1_ + ca1];
                    q0 += h0 * lds[OFF_WLDS + (m    ) * G1_ + cb1];
                    q1 += h1 * lds[OFF_WLDS + (m + 1) * G1_ + cb1];
                    q2 += h2 * lds[OFF_WLDS + (m + 2) * G1_ + cb1];
                    q3 += h3 * lds[OFF_WLDS + (m + 3) * G1_ + cb1];
                }
                lds[OFF_ZBUF + ca1] = (p0 + p1) + (p2 + p3);
                lds[OFF_ZBUF + cb1] = (q0 + q1) + (q2 + q3);
            }
            __syncthreads();
            if (j < H1_) {
                float zi = lds[OFF_ZBUF + j];
                float zf = lds[OFF_ZBUF + H1_ + j];
                float zg = lds[OFF_ZBUF + 2 * H1_ + j];
                float zo = lds[OFF_ZBUF + 3 * H1_ + j];
                float ig = sigm(zi);
                float fg = sigm(zf);
                float gg = fmaxf(zg, 0.0f);
                float og = sigm(zo);
                c1 = fg * c1 + ig * gg;
                float h = og * fmaxf(c1, 0.0f);
                lds[OFF_H1S + j] = h;
                lds[OFF_H1C + t * H1_ + j] = h;
            }
            __syncthreads();
        }

        // ---- A2 pass 1: xp2[t][c] = b2[c] + h1_t[0:64] . W2[0:64,c] ----
        // (xp2 overlays xs/xp1 — dead after A1's final barrier)
        {
            LS16(W2, G2_, 0, ca2, cb2)
            const float ba = b2[ca2], bb = b2[cb2];
            for (int t = 0; t < TC; ++t) {
                const float4* hb4 = (const float4*)&lds[OFF_H1C + t * H1_];
                float p0 = ba, p1 = 0.f, p2 = 0.f, p3 = 0.f;
                float q0 = bb, q1 = 0.f, q2 = 0.f, q3 = 0.f;
                REP16(DOT2)
                lds[OFF_XP2 + t * G2_ + ca2] = (p0 + p1) + (p2 + p3);
                lds[OFF_XP2 + t * G2_ + cb2] = (q0 + q1) + (q2 + q3);
            }
        }
        // ---- A2 pass 2: += h1_t[64:100] . W2[64:100,c] (same owner, no barrier) ----
        {
            LS9(W2, G2_, 64, ca2, cb2)
            for (int t = 0; t < TC; ++t) {
                const float4* hb4 = (const float4*)&lds[OFF_H1C + t * H1_ + 64];
                float p0 = 0.f, p1 = 0.f, p2 = 0.f, p3 = 0.f;
                float q0 = 0.f, q1 = 0.f, q2 = 0.f, q3 = 0.f;
                REP9(DOT2)
                lds[OFF_XP2 + t * G2_ + ca2] += (p0 + p1) + (p2 + p3);
                lds[OFF_XP2 + t * G2_ + cb2] += (q0 + q1) + (q2 + q3);
            }
        }
        // ---- U2 rows 0..79 into regs (20 f4 x2); rows 80..127 -> WLDS (6144 f4) ----
        LS20(U2, G2_, 0, ca2, cb2)
        {
            const float4* s4 = (const float4*)(U2 + U2_RREG * G2_);
            float4* d4 = (float4*)&lds[OFF_WLDS];
            #pragma unroll
            for (int r = 0; r < 24; ++r)
                d4[r * NT + j] = s4[r * NT + j];
        }
        __syncthreads();   // xp2 + WLDS(U2part) ready

        // ---- B: layer-2 recurrence ----
        for (int t = 0; t < TC; ++t) {
            {
                const float4* hb4 = (const float4*)&lds[OFF_H2S];
                float p0 = lds[OFF_XP2 + t * G2_ + ca2], p1 = 0.f, p2 = 0.f, p3 = 0.f;
                float q0 = lds[OFF_XP2 + t * G2_ + cb2], q1 = 0.f, q2 = 0.f, q3 = 0.f;
                REP20(DOT2)                        // rows 0..79 from regs
                #pragma unroll
                for (int m = 0; m < H2_ - U2_RREG; m += 4) {  // rows 80..127 from LDS
                    float h0 = lds[OFF_H2S + U2_RREG + m    ];
                    float h1 = lds[OFF_H2S + U2_RREG + m + 1];
                    float h2 = lds[OFF_H2S + U2_RREG + m + 2];
                    float h3 = lds[OFF_H2S + U2_RREG + m + 3];
                    p0 += h0 * lds[OFF_WLDS + (m    ) * G2_ + ca2];
                    p1 += h1 * lds[OFF_WLDS + (m + 1) * G2_ + ca2];
                    p2 += h2 * lds[OFF_WLDS + (m + 2) * G2_ + ca2];
                    p3 += h3 * lds[OFF_WLDS + (m + 3) * G2_ + ca2];
                    q0 += h0 * lds[OFF_WLDS + (m    ) * G2_ + cb2];
                    q1 += h1 * lds[OFF_WLDS + (m + 1) * G2_ + cb2];
                    q2 += h2 * lds[OFF_WLDS + (m + 2) * G2_ + cb2];
                    q3 += h3 * lds[OFF_WLDS + (m + 3) * G2_ + cb2];
                }
                lds[OFF_ZBUF + ca2] = (p0 + p1) + (p2 + p3);
                lds[OFF_ZBUF + cb2] = (q0 + q1) + (q2 + q3);
            }
            __syncthreads();
            if (j < H2_) {
                float zi = lds[OFF_ZBUF + j];
                float zf = lds[OFF_ZBUF + H2_ + j];
                float zg = lds[OFF_ZBUF + 2 * H2_ + j];
                float zo = lds[OFF_ZBUF + 3 * H2_ + j];
                float ig = sigm(zi);
                float fg = sigm(zf);
                float gg = fmaxf(zg, 0.0f);
                float og = sigm(zo);
                c2 = fg * c2 + ig * gg;
                float h = og * fmaxf(c2, 0.0f);
                lds[OFF_H2S + j] = h;
            }
            __syncthreads();
        }
    }

    // ---- head: logits = h2_last @ Wd + bd ; softmax over 19 ----
    if (j < OUT_) {
        float acc = bd[j];
        #pragma unroll
        for (int k = 0; k < H2_; ++k) acc += lds[OFF_H2S + k] * Wd[k * OUT_ + j];
        lds[OFF_ZBUF + j] = acc;
    }
    __syncthreads();
    if (j < OUT_) {
        float m = -1e30f;
        for (int k = 0; k < OUT_; ++k) m = fmaxf(m, lds[OFF_ZBUF + k]);
        float s = 0.0f;
        for (int k = 0; k < OUT_; ++k) s += expf(lds[OFF_ZBUF + k] - m);
        out[b * OUT_ + j] = expf(lds[OFF_ZBUF + j] - m) / s;
    }
}

extern "C" void kernel_launch(void* const* d_in, const int* in_sizes, int n_in,
                              void* d_out, int out_size, void* d_ws, size_t ws_size,
                              hipStream_t stream) {
    const float* x  = (const float*)d_in[0];
    const float* W1 = (const float*)d_in[1];
    const float* U1 = (const float*)d_in[2];
    const float* b1 = (const float*)d_in[3];
    const float* W2 = (const float*)d_in[4];
    const float* U2 = (const float*)d_in[5];
    const float* b2 = (const float*)d_in[6];
    const float* Wd = (const float*)d_in[7];
    const float* bd = (const float*)d_in[8];
    float* out = (float*)d_out;

    hipLaunchKernelGGL(lstm_fused, dim3(B_), dim3(NT), 0, stream,
                       x, W1, U1, b1, W2, U2, b2, Wd, bd, out);
}

// Round 9
// 3289.088 us; speedup vs baseline: 3.4519x; 3.4519x over previous
//
#include <hip/hip_runtime.h>
#include <math.h>

// Problem dims
#define B_   256
#define T_   512
#define F_   64
#define H1_  100
#define H2_  128
#define OUT_ 19
#define G1_  400   // 4*H1
#define G2_  512   // 4*H2
#define TC   32    // timesteps per chunk
#define NCHUNK (T_/TC)

typedef unsigned int uint;
typedef _Float16 h16;
typedef __attribute__((ext_vector_type(2))) _Float16 h16x2;

// ---- LDS layout (BYTE offsets), phase-overlaid ----
// xp1 fp32[32][400]        [0, 51200)        A0 write -> A1 read
// xp2 fp16[32][512]        [0, 32768)        A2 write -> B read   (overlays xp1)
// WQ  (W1: 8q x400 x16B)   [51200, 102400)   A0
//     (U1: 13q x400 x16B)  [51200, 134400)   A1                   (overlays W1)
// XS  fp16-pairs 1024 u32  [134400, 138496)  A0
// W2Q 13q x512 x16B        [32768, 139264)   A2                   (overlays U1, dead xp1 tail)
// H1C fp16 32t x 208B      [139264, 145920)  A1 write -> A2 read
// U2Q 15q x512 x16B        [32768, 155648)   B                    (overlays W2Q, dead H1C)
// ZBUF fp32[512]           [160000, 162048)
// H1PK 13 u32x4 (104 h)    [162048, 162256)
// H2PK 16 u32x4 (128 h)    [162256, 162512)
// H2F  fp32[128]           [162512, 163024)
#define OFF_XP1  0
#define OFF_XP2  0
#define OFF_WQ   51200
#define OFF_XS   134400
#define OFF_W2Q  32768
#define OFF_H1C  139264
#define OFF_U2Q  32768
#define OFF_ZBUF 160000
#define OFF_H1PK 162048
#define OFF_H2PK 162256
#define OFF_H2F  162512
#define LDS_BYTES 163328   // same size as R6 (known to launch)

__device__ __forceinline__ float sigm(float x) {
    return 1.0f / (1.0f + __expf(-x));
}

__device__ __forceinline__ uint pk2(float a, float b) {
    h16x2 h; h.x = (h16)a; h.y = (h16)b;
    return __builtin_bit_cast(uint, h);
}

// fp16-pair dot with fp32 accumulate: c + a.x*b.x + a.y*b.y
__device__ __forceinline__ float fd2(uint w, uint h, float c) {
#if __has_builtin(__builtin_amdgcn_fdot2)
    return __builtin_amdgcn_fdot2(__builtin_bit_cast(h16x2, w),
                                  __builtin_bit_cast(h16x2, h), c, false);
#else
    h16x2 a = __builtin_bit_cast(h16x2, w), b = __builtin_bit_cast(h16x2, h);
    return c + (float)a.x * (float)b.x + (float)a.y * (float)b.y;
#endif
}

// Stage fp32 matrix P[K x G] (k-major) into LDS as fp16 quad-rows:
// uint4 at dst + (q*G + j)*16 holds pairs (8q,8q+1),(8q+2,8q+3),... of column j.
// Rows >= KREAL are zero-padded. Coalesced: lane-consecutive j per (q,r).
__device__ __forceinline__ void stage_quads(const float* __restrict__ P, const int G,
                                            const int NQ, const int KREAL,
                                            char* dst, const int j)
{
    if (j < G) {
        for (int q = 0; q < NQ; ++q) {
            float f[8];
            #pragma unroll
            for (int r = 0; r < 8; ++r) {
                const int k = 8 * q + r;
                f[r] = (k < KREAL) ? P[(size_t)k * G + j] : 0.0f;
            }
            uint4 u;
            u.x = pk2(f[0], f[1]); u.y = pk2(f[2], f[3]);
            u.z = pk2(f[4], f[5]); u.w = pk2(f[6], f[7]);
            *(uint4*)(dst + (size_t)(q * G + j) * 16) = u;
        }
    }
}

__global__ __launch_bounds__(512)
void lstm_fused(
    const float* __restrict__ x,
    const float* __restrict__ W1, const float* __restrict__ U1, const float* __restrict__ b1,
    const float* __restrict__ W2, const float* __restrict__ U2, const float* __restrict__ b2,
    const float* __restrict__ Wd, const float* __restrict__ bd,
    float* __restrict__ out)
{
    __shared__ uint4 smem4[LDS_BYTES / 16];
    char* sm = (char*)smem4;
    const int b = blockIdx.x;
    const int j = threadIdx.x;

    float c1 = 0.0f;   // gate thread j<100 owns c1[j]
    float c2 = 0.0f;   // gate thread j<128 owns c2[j]

    // U2 rows 120..127 (pairs 60..63) as 4 named uints — loaded ONCE (8 scalar loads)
    const uint u2r0 = pk2(U2[120 * G2_ + j], U2[121 * G2_ + j]);
    const uint u2r1 = pk2(U2[122 * G2_ + j], U2[123 * G2_ + j]);
    const uint u2r2 = pk2(U2[124 * G2_ + j], U2[125 * G2_ + j]);
    const uint u2r3 = pk2(U2[126 * G2_ + j], U2[127 * G2_ + j]);

    // init packed-h buffers and h1c (zeros; pads stay zero forever)
    if (j < 52) *(uint*)(sm + OFF_H1PK + 4 * j) = 0u;
    if (j < 64) *(uint*)(sm + OFF_H2PK + 4 * j) = 0u;
    #pragma unroll
    for (int r = 0; r < 4; ++r) {
        int idx = r * 512 + j;
        if (idx < 1664) *(uint*)(sm + OFF_H1C + 4 * idx) = 0u;  // 6656 B
    }
    __syncthreads();

    const float* xrow = x + (size_t)b * T_ * F_;

    for (int ch = 0; ch < NCHUNK; ++ch) {
        // ---- stage W1 (8 quads) + xs (x pairs) ----
        stage_quads(W1, G1_, 8, 64, sm + OFF_WQ, j);
        {
            #pragma unroll
            for (int r = 0; r < 2; ++r) {
                int v = r * 512 + j;                      // v = t*32 + pair
                float2 xv = *(const float2*)(xrow + ch * (TC * F_) + 2 * v);
                *(uint*)(sm + OFF_XS + 4 * v) = pk2(xv.x, xv.y);
            }
        }
        __syncthreads();

        // ---- A0: xp1[t][j] = b1[j] + x_t . W1col_j (no internal barriers) ----
        if (j < G1_) {
            const float bj = b1[j];
            const uint4* WQ = (const uint4*)(sm + OFF_WQ);
            for (int t = 0; t < TC; ++t) {
                const uint4* XQ = (const uint4*)(sm + OFF_XS + t * 128);
                float a0 = bj, a1 = 0.f, a2 = 0.f, a3 = 0.f;
                #pragma unroll
                for (int q = 0; q < 8; ++q) {
                    uint4 w = WQ[q * G1_ + j];
                    uint4 hp = XQ[q];
                    a0 = fd2(w.x, hp.x, a0); a1 = fd2(w.y, hp.y, a1);
                    a2 = fd2(w.z, hp.z, a2); a3 = fd2(w.w, hp.w, a3);
                }
                *(float*)(sm + OFF_XP1 + 4 * (t * G1_ + j)) = (a0 + a1) + (a2 + a3);
            }
        }
        __syncthreads();   // A0 done (W1 dead, xp1 complete)

        // ---- stage U1 (13 quads, rows 0..99, pad 100..103 = 0) ----
        stage_quads(U1, G1_, 13, H1_, sm + OFF_WQ, j);
        __syncthreads();

        // ---- A1: layer-1 recurrence ----
        for (int t = 0; t < TC; ++t) {
            if (j < G1_) {
                const uint4* WQ = (const uint4*)(sm + OFF_WQ);
                const uint4* HP = (const uint4*)(sm + OFF_H1PK);
                float a0 = *(const float*)(sm + OFF_XP1 + 4 * (t * G1_ + j));
                float a1 = 0.f, a2 = 0.f, a3 = 0.f;
                #pragma unroll
                for (int q = 0; q < 13; ++q) {
                    uint4 w = WQ[q * G1_ + j];
                    uint4 hp = HP[q];
                    a0 = fd2(w.x, hp.x, a0); a1 = fd2(w.y, hp.y, a1);
                    a2 = fd2(w.z, hp.z, a2); a3 = fd2(w.w, hp.w, a3);
                }
                *(float*)(sm + OFF_ZBUF + 4 * j) = (a0 + a1) + (a2 + a3);
            }
            __syncthreads();
            if (j < H1_) {
                const float* zb = (const float*)(sm + OFF_ZBUF);
                float ig = sigm(zb[j]);
                float fg = sigm(zb[H1_ + j]);
                float gg = fmaxf(zb[2 * H1_ + j], 0.0f);
                float og = sigm(zb[3 * H1_ + j]);
                c1 = fg * c1 + ig * gg;
                float h = og * fmaxf(c1, 0.0f);
                h16 hh = (h16)h;
                *(h16*)(sm + OFF_H1PK + 2 * j) = hh;
                *(h16*)(sm + OFF_H1C + t * 208 + 2 * j) = hh;
            }
            __syncthreads();
        }

        // ---- stage W2 (13 quads, rows 0..99 + zero pad) ----
        stage_quads(W2, G2_, 13, H1_, sm + OFF_W2Q, j);
        __syncthreads();

        // ---- A2: xp2[t][j] = b2[j] + h1_t . W2col_j (no internal barriers) ----
        {
            const float bj = b2[j];
            const uint4* WQ = (const uint4*)(sm + OFF_W2Q);
            for (int t = 0; t < TC; ++t) {
                const uint4* HC = (const uint4*)(sm + OFF_H1C + t * 208);
                float a0 = bj, a1 = 0.f, a2 = 0.f, a3 = 0.f;
                #pragma unroll
                for (int q = 0; q < 13; ++q) {
                    uint4 w = WQ[q * G2_ + j];
                    uint4 hp = HC[q];
                    a0 = fd2(w.x, hp.x, a0); a1 = fd2(w.y, hp.y, a1);
                    a2 = fd2(w.z, hp.z, a2); a3 = fd2(w.w, hp.w, a3);
                }
                *(h16*)(sm + OFF_XP2 + 2 * (t * G2_ + j)) = (h16)((a0 + a1) + (a2 + a3));
            }
        }
        __syncthreads();   // xp2 complete, W2/h1c dead

        // ---- stage U2 rows 0..119 (15 quads) ----
        stage_quads(U2, G2_, 15, 120, sm + OFF_U2Q, j);
        __syncthreads();

        // ---- B: layer-2 recurrence ----
        for (int t = 0; t < TC; ++t) {
            {
                const uint4* WQ = (const uint4*)(sm + OFF_U2Q);
                const uint4* HP = (const uint4*)(sm + OFF_H2PK);
                float a0 = (float)*(const h16*)(sm + OFF_XP2 + 2 * (t * G2_ + j));
                float a1 = 0.f, a2 = 0.f, a3 = 0.f;
                #pragma unroll
                for (int q = 0; q < 15; ++q) {
                    uint4 w = WQ[q * G2_ + j];
                    uint4 hp = HP[q];
                    a0 = fd2(w.x, hp.x, a0); a1 = fd2(w.y, hp.y, a1);
                    a2 = fd2(w.z, hp.z, a2); a3 = fd2(w.w, hp.w, a3);
                }
                uint4 hp15 = ((const uint4*)(sm + OFF_H2PK))[15];   // rows 120..127
                a0 = fd2(u2r0, hp15.x, a0); a1 = fd2(u2r1, hp15.y, a1);
                a2 = fd2(u2r2, hp15.z, a2); a3 = fd2(u2r3, hp15.w, a3);
                *(float*)(sm + OFF_ZBUF + 4 * j) = (a0 + a1) + (a2 + a3);
            }
            __syncthreads();
            if (j < H2_) {
                const float* zb = (const float*)(sm + OFF_ZBUF);
                float ig = sigm(zb[j]);
                float fg = sigm(zb[H2_ + j]);
                float gg = fmaxf(zb[2 * H2_ + j], 0.0f);
                float og = sigm(zb[3 * H2_ + j]);
                c2 = fg * c2 + ig * gg;
                float h = og * fmaxf(c2, 0.0f);
                *(h16*)(sm + OFF_H2PK + 2 * j) = (h16)h;
                *(float*)(sm + OFF_H2F + 4 * j) = h;
            }
            __syncthreads();
        }
    }

    // ---- head: logits = h2_last @ Wd + bd ; softmax over 19 (fp32) ----
    if (j < OUT_) {
        const float* h2 = (const float*)(sm + OFF_H2F);
        float acc = bd[j];
        #pragma unroll
        for (int k = 0; k < H2_; ++k) acc += h2[k] * Wd[k * OUT_ + j];
        *(float*)(sm + OFF_ZBUF + 4 * j) = acc;
    }
    __syncthreads();
    if (j < OUT_) {
        const float* zb = (const float*)(sm + OFF_ZBUF);
        float m = -1e30f;
        for (int k = 0; k < OUT_; ++k) m = fmaxf(m, zb[k]);
        float s = 0.0f;
        for (int k = 0; k < OUT_; ++k) s += expf(zb[k] - m);
        out[b * OUT_ + j] = expf(zb[j] - m) / s;
    }
}

extern "C" void kernel_launch(void* const* d_in, const int* in_sizes, int n_in,
                              void* d_out, int out_size, void* d_ws, size_t ws_size,
                              hipStream_t stream) {
    const float* x  = (const float*)d_in[0];
    const float* W1 = (const float*)d_in[1];
    const float* U1 = (const float*)d_in[2];
    const float* b1 = (const float*)d_in[3];
    const float* W2 = (const float*)d_in[4];
    const float* U2 = (const float*)d_in[5];
    const float* b2 = (const float*)d_in[6];
    const float* Wd = (const float*)d_in[7];
    const float* bd = (const float*)d_in[8];
    float* out = (float*)d_out;

    hipLaunchKernelGGL(lstm_fused, dim3(B_), dim3(512), 0, stream,
                       x, W1, U1, b1, W2, U2, b2, Wd, bd, out);
}